// Round 1
// baseline (438.544 us; speedup 1.0000x reference)
//
#include <hip/hip_runtime.h>

__device__ __forceinline__ float2 cmulf(float2 a, float c, float s) {
    return make_float2(a.x * c - a.y * s, a.x * s + a.y * c);
}

// LDS index swizzle: bijective on [0,2048), spreads the radix-4 scattered
// writes (lane strides = multiples of 16 float2) across all banks.
#define SW(e) ((e) ^ ((e) >> 4))

// One workgroup = one row of length 4096.
// Makhoul half-spectrum + 2048-pt complex IFFT (Stockham).
// Stage 0 (radix-4) fused into the register prologue; final radix-2 fused
// into the de-interleave store. All twiddles come from the expk table
// (expk[k] = exp(i*pi*k/8192), k<4096) instead of __sincosf.
template<bool IDXST>
__global__ __launch_bounds__(256)
void row_fft_kernel(const float* in, float* out, const float2* __restrict__ expk)
{
    __shared__ float2 bufA[2048];
    __shared__ float2 bufB[2048];

    const int t = threadIdx.x;
    const size_t row = blockIdx.x;
    const float* src = in  + row * 4096;
    float*       dst = out + row * 4096;

    // ---- prologue: Z_k = A_k + i*B_k built in registers (k = t + 256*i) ----
    // V_k = 0.5*(X_k - i*Xr_k)*expk[k]
    // A_k = V_k + V_{k+2048}; B_k = (V_k - V_{k+2048}) * exp(i*pi*k/2048)
    float2 z[8];
    #pragma unroll
    for (int i = 0; i < 8; i++) {
        int k = t + 256 * i;                  // 0..2047
        float Xa, Xra, Xb, Xrb;
        if (IDXST) {
            Xa  = src[(4096 - k) & 4095];
            Xra = src[k];
            Xb  = src[2048 - k];
            Xrb = src[2048 + k];
            if (k == 0) { Xa = 0.0f; Xra = 0.0f; }
        } else {
            Xa  = src[k];
            Xra = src[(4096 - k) & 4095];
            Xb  = src[2048 + k];
            Xrb = src[2048 - k];
            if (k == 0) Xra = 0.0f;
        }
        float2 ea = expk[k];
        float2 eb = expk[k + 2048];
        float Var = 0.5f * (Xa * ea.x + Xra * ea.y);
        float Vai = 0.5f * (Xa * ea.y - Xra * ea.x);
        float Vbr = 0.5f * (Xb * eb.x + Xrb * eb.y);
        float Vbi = 0.5f * (Xb * eb.y - Xrb * eb.x);
        float Ar = Var + Vbr, Ai = Vai + Vbi;
        float Dr = Var - Vbr, Di = Vai - Vbi;
        // exp(i*pi*k/2048) = expk[4k] for k<1024, else i*expk[4k-4096]
        int k4 = 4 * k;
        float2 et = expk[k4 & 4095];
        bool hi = (k4 >= 4096);
        float cw = hi ? -et.y : et.x;
        float sw = hi ?  et.x : et.y;
        float Br = Dr * cw - Di * sw;
        float Bi = Dr * sw + Di * cw;
        z[i] = make_float2(Ar - Bi, Ai + Br);    // A + i*B
    }

    // ---- stage 0: radix-4, Ns=1 (twiddle-free), straight from registers ----
    // item j = t + 256*ii reads Z[j], Z[j+512], Z[j+1024], Z[j+1536]
    //   = z[ii], z[ii+2], z[ii+4], z[ii+6]
    #pragma unroll
    for (int ii = 0; ii < 2; ii++) {
        float2 v0 = z[ii], v1 = z[ii + 2], v2 = z[ii + 4], v3 = z[ii + 6];
        float a0r = v0.x + v2.x, a0i = v0.y + v2.y;
        float a1r = v0.x - v2.x, a1i = v0.y - v2.y;
        float a2r = v1.x + v3.x, a2i = v1.y + v3.y;
        float a3r = v1.x - v3.x, a3i = v1.y - v3.y;
        int idxD = (t + 256 * ii) << 2;
        bufA[SW(idxD)]     = make_float2(a0r + a2r, a0i + a2i);
        bufA[SW(idxD + 1)] = make_float2(a1r - a3i, a1i + a3r);   // a1 + i*a3
        bufA[SW(idxD + 2)] = make_float2(a0r - a2r, a0i - a2i);
        bufA[SW(idxD + 3)] = make_float2(a1r + a3i, a1i - a3r);   // a1 - i*a3
    }
    __syncthreads();

    // ---- radix-4 stages, Ns = 4,16,64,256 ----
    float2* sb = bufA;
    float2* db = bufB;
    int Ns = 4;
    #pragma unroll
    for (int s = 1; s < 5; s++) {
        const int ls = 2 * s;
        const int shift = 12 - 2 * s;         // twiddle idx = jm * 4096/Ns
        #pragma unroll
        for (int ii = 0; ii < 2; ii++) {
            int j = t + 256 * ii;             // 0..511
            float2 v0 = sb[SW(j)];
            float2 v1 = sb[SW(j + 512)];
            float2 v2 = sb[SW(j + 1024)];
            float2 v3 = sb[SW(j + 1536)];
            int jm = j & (Ns - 1);
            float2 e1 = expk[jm << shift];    // exp(i*pi*jm/(2*Ns)), idx < 4096
            float c1 = e1.x, s1 = e1.y;
            float c2 = c1 * c1 - s1 * s1, s2 = 2.0f * c1 * s1;
            float c3 = c1 * c2 - s1 * s2, s3 = c1 * s2 + s1 * c2;
            v1 = cmulf(v1, c1, s1);
            v2 = cmulf(v2, c2, s2);
            v3 = cmulf(v3, c3, s3);
            float a0r = v0.x + v2.x, a0i = v0.y + v2.y;
            float a1r = v0.x - v2.x, a1i = v0.y - v2.y;
            float a2r = v1.x + v3.x, a2i = v1.y + v3.y;
            float a3r = v1.x - v3.x, a3i = v1.y - v3.y;
            int idxD = ((j >> ls) << (ls + 2)) | jm;
            db[SW(idxD)]          = make_float2(a0r + a2r, a0i + a2i);
            db[SW(idxD + Ns)]     = make_float2(a1r - a3i, a1i + a3r);
            db[SW(idxD + 2 * Ns)] = make_float2(a0r - a2r, a0i - a2i);
            db[SW(idxD + 3 * Ns)] = make_float2(a1r + a3i, a1i - a3r);
        }
        __syncthreads();
        float2* tmp = sb; sb = db; db = tmp;
        Ns <<= 2;
    }
    // after swaps: sb == bufA holds the radix-2 stage input

    // ---- fused radix-2 (Ns=1024) + de-interleave + float4 store ----
    // pair items jA = j (<512) and jB = 1023-j so each thread holds
    // z[jA], z[jA+1024], z[jB], z[jB+1024] -> outputs p=jA and p=jB.
    // y_{4p} = Re z_p ; y_{4p+1} = Im z_{2047-p} ; y_{4p+2} = Im z_p ;
    // y_{4p+3} = Re z_{2047-p}  (odd outputs negated for IDXST)
    float4* d4 = (float4*)dst;
    #pragma unroll
    for (int ii = 0; ii < 2; ii++) {
        int j  = t + 256 * ii;                // 0..511
        int jB = 1023 - j;
        float2 a0 = sb[SW(j)];
        float2 a1 = sb[SW(j + 1024)];
        float2 b0 = sb[SW(jB)];
        float2 b1 = sb[SW(jB + 1024)];
        // w(j)  = exp(i*pi*j/1024)        = expk[8j]           (8j <= 4088)
        // w(jB) = exp(i*pi*(1023-j)/1024) = i*expk[8*(511-j)]
        float2 eA = expk[8 * j];
        float2 eB = expk[8 * (511 - j)];
        float2 wa1 = cmulf(a1, eA.x, eA.y);
        float2 wb1 = cmulf(b1, -eB.y, eB.x);
        float2 zA0 = make_float2(a0.x + wa1.x, a0.y + wa1.y);   // z[j]
        float2 zA1 = make_float2(a0.x - wa1.x, a0.y - wa1.y);   // z[j+1024]
        float2 zB0 = make_float2(b0.x + wb1.x, b0.y + wb1.y);   // z[jB]
        float2 zB1 = make_float2(b0.x - wb1.x, b0.y - wb1.y);   // z[jB+1024] = z[2047-j]
        float4 oA, oB;
        if (IDXST) {
            oA = make_float4(zA0.x, -zB1.y, zA0.y, -zB1.x);
            oB = make_float4(zB0.x, -zA1.y, zB0.y, -zA1.x);
        } else {
            oA = make_float4(zA0.x,  zB1.y, zA0.y,  zB1.x);
            oB = make_float4(zB0.x,  zA1.y, zB0.y,  zA1.x);
        }
        d4[j]  = oA;
        d4[jB] = oB;
    }
}

// In-place per-batch square transpose (n x n), 64x64 tile pairs.
// float4 global loads AND stores; scalar LDS ops into padded tiles
// (bank = (4*c4 + j + r) mod 32 is at most 2-way = free).
__global__ __launch_bounds__(256)
void transpose_inplace(float* d, int n)
{
    __shared__ float ta[64][65];
    __shared__ float tb[64][65];
    int ti = blockIdx.x, tj = blockIdx.y, b = blockIdx.z;
    if (tj < ti) return;
    float* base = d + (size_t)b * n * n;
    const int t  = threadIdx.x;               // 0..255
    const int c4 = t & 15;                    // float4 column
    const int r0 = t >> 4;                    // 0..15
    size_t offA = (size_t)(ti * 64) * n + tj * 64;
    size_t offB = (size_t)(tj * 64) * n + ti * 64;

    #pragma unroll
    for (int q = 0; q < 4; q++) {
        int r = r0 + 16 * q;
        float4 va = ((const float4*)(base + offA + (size_t)r * n))[c4];
        ta[r][4 * c4 + 0] = va.x; ta[r][4 * c4 + 1] = va.y;
        ta[r][4 * c4 + 2] = va.z; ta[r][4 * c4 + 3] = va.w;
    }
    if (ti != tj) {
        #pragma unroll
        for (int q = 0; q < 4; q++) {
            int r = r0 + 16 * q;
            float4 vb = ((const float4*)(base + offB + (size_t)r * n))[c4];
            tb[r][4 * c4 + 0] = vb.x; tb[r][4 * c4 + 1] = vb.y;
            tb[r][4 * c4 + 2] = vb.z; tb[r][4 * c4 + 3] = vb.w;
        }
    }
    __syncthreads();

    if (ti != tj) {
        #pragma unroll
        for (int q = 0; q < 4; q++) {
            int r = r0 + 16 * q;
            float4 o;
            o.x = tb[4 * c4 + 0][r]; o.y = tb[4 * c4 + 1][r];
            o.z = tb[4 * c4 + 2][r]; o.w = tb[4 * c4 + 3][r];
            ((float4*)(base + offA + (size_t)r * n))[c4] = o;
            float4 p;
            p.x = ta[4 * c4 + 0][r]; p.y = ta[4 * c4 + 1][r];
            p.z = ta[4 * c4 + 2][r]; p.w = ta[4 * c4 + 3][r];
            ((float4*)(base + offB + (size_t)r * n))[c4] = p;
        }
    } else {
        #pragma unroll
        for (int q = 0; q < 4; q++) {
            int r = r0 + 16 * q;
            float4 p;
            p.x = ta[4 * c4 + 0][r]; p.y = ta[4 * c4 + 1][r];
            p.z = ta[4 * c4 + 2][r]; p.w = ta[4 * c4 + 3][r];
            ((float4*)(base + offA + (size_t)r * n))[c4] = p;
        }
    }
}

extern "C" void kernel_launch(void* const* d_in, const int* in_sizes, int n_in,
                              void* d_out, int out_size, void* d_ws, size_t ws_size,
                              hipStream_t stream)
{
    const float*  x     = (const float*)d_in[0];
    const float2* expkM = (const float2*)d_in[1];   // (4096, 2) fp32
    const float2* expkN = (const float2*)d_in[2];   // (4096, 2) fp32
    float* out = (float*)d_out;

    const int B = in_sizes[0] / (4096 * 4096);      // = 2
    const int rows = B * 4096;

    // IDXST along N (contiguous rows of x) -> out.  (Transforms on M and N commute.)
    row_fft_kernel<true><<<rows, 256, 0, stream>>>(x, out, expkN);
    // out: (B, M, N) -> (B, N, M)
    transpose_inplace<<<dim3(64, 64, B), dim3(256), 0, stream>>>(out, 4096);
    // IDCT along M (now-contiguous rows), in place.
    row_fft_kernel<false><<<rows, 256, 0, stream>>>(out, out, expkM);
    // back to (B, M, N)
    transpose_inplace<<<dim3(64, 64, B), dim3(256), 0, stream>>>(out, 4096);
}

// Round 2
// 368.869 us; speedup vs baseline: 1.1889x; 1.1889x over previous
//
#include <hip/hip_runtime.h>

#define PI_F 3.14159265358979323846f

__device__ __forceinline__ float2 cmulf(float2 a, float c, float s) {
    return make_float2(a.x * c - a.y * s, a.x * s + a.y * c);
}

// LDS float2-index swizzle: XOR low4 with 5*((e>>4)&3).
// Wide-bank = float2-index mod 16. Hand-verified conflict-free for every
// access pattern in this kernel:
//   reads  e = t + {0,512,1024,1536}, reversed runs, e = t, t+1024      (uniform)
//   stage0 writes e = 4t+c      : low4=(4u+c), v=(m>>2) -> bits01=c^v, bits23=u^v
//   Ns=4   writes e = 16v'+4c+u : low4=(4c+u), v=(m>>2) -> bits01=u^v, bits23=c^v
//   Ns>=16 writes               : low4=m, XOR-mask constant per 16-lane group
#define SW(e) ((e) ^ ((((e) >> 4) & 3) * 5))

// One workgroup (512 threads) = one row of length 4096.
// Makhoul half-spectrum + 2048-pt complex IFFT (Stockham radix-4).
// Stage 0 fused into the register prologue; final radix-2 fused into the
// de-interleave store. One butterfly per thread in every stage.
template<bool IDXST>
__global__ __launch_bounds__(512, 8)
void row_fft_kernel(const float* __restrict__ in, float* __restrict__ out,
                    const float2* __restrict__ expk)
{
    __shared__ float smem[8192];               // 32 KB
    float*  xs   = smem;                       // staged row [4096] (dead at Ns=4)
    float2* bufB = (float2*)smem;              // overlays xs
    float2* bufA = (float2*)(smem + 4096);

    const int t = threadIdx.x;                 // 0..511
    const size_t row = blockIdx.x;
    const float* src = in  + row * 4096;
    float*       dst = out + row * 4096;

    // ---- stage row into LDS, coalesced float4 ----
    {
        const float4* s4 = (const float4*)src;
        float4* x4 = (float4*)xs;
        x4[t]       = s4[t];
        x4[t + 512] = s4[t + 512];
    }
    __syncthreads();

    // ---- prologue: Z_k = A_k + i*B_k in registers (k = t + 512*i) ----
    // V_k = 0.5*(X_k - i*Xr_k)*expk[k]
    // A_k = V_k + V_{k+2048}; B_k = (V_k - V_{k+2048}) * exp(i*pi*k/2048)
    float2 z[4];
    #pragma unroll
    for (int i = 0; i < 4; i++) {
        int k = t + 512 * i;                   // 0..2047
        float Xa, Xra, Xb, Xrb;
        if (IDXST) {
            Xa  = xs[(4096 - k) & 4095];
            Xra = xs[k];
            Xb  = xs[2048 - k];
            Xrb = xs[2048 + k];
            if (k == 0) { Xa = 0.0f; Xra = 0.0f; }
        } else {
            Xa  = xs[k];
            Xra = xs[(4096 - k) & 4095];
            Xb  = xs[2048 + k];
            Xrb = xs[2048 - k];
            if (k == 0) Xra = 0.0f;
        }
        float2 ea = expk[k];                   // coalesced L1/L2 reads
        float2 eb = expk[k + 2048];
        float Var = 0.5f * (Xa * ea.x + Xra * ea.y);
        float Vai = 0.5f * (Xa * ea.y - Xra * ea.x);
        float Vbr = 0.5f * (Xb * eb.x + Xrb * eb.y);
        float Vbi = 0.5f * (Xb * eb.y - Xrb * eb.x);
        float Ar = Var + Vbr, Ai = Vai + Vbi;
        float Dr = Var - Vbr, Di = Vai - Vbi;
        float cw, sw;                          // exp(i*pi*k/2048)
        __sincosf(PI_F * (float)k * (1.0f / 2048.0f), &sw, &cw);
        float Br = Dr * cw - Di * sw;
        float Bi = Dr * sw + Di * cw;
        z[i] = make_float2(Ar - Bi, Ai + Br);  // A + i*B
    }

    // ---- fused radix-4 stage 0 (Ns=1, twiddle-free): item j = t ----
    // inputs Z[t + 512c] = z[c]
    {
        float2 v0 = z[0], v1 = z[1], v2 = z[2], v3 = z[3];
        float a0r = v0.x + v2.x, a0i = v0.y + v2.y;
        float a1r = v0.x - v2.x, a1i = v0.y - v2.y;
        float a2r = v1.x + v3.x, a2i = v1.y + v3.y;
        float a3r = v1.x - v3.x, a3i = v1.y - v3.y;
        int e = t << 2;
        bufA[SW(e)]     = make_float2(a0r + a2r, a0i + a2i);
        bufA[SW(e + 1)] = make_float2(a1r - a3i, a1i + a3r);   // a1 + i*a3
        bufA[SW(e + 2)] = make_float2(a0r - a2r, a0i - a2i);
        bufA[SW(e + 3)] = make_float2(a1r + a3i, a1i - a3r);   // a1 - i*a3
    }
    __syncthreads();

    // ---- radix-4 stages, Ns = 4,16,64,256; one butterfly per thread ----
    float2* sb = bufA;
    float2* db = bufB;
    int Ns = 4;
    #pragma unroll
    for (int s = 1; s < 5; s++) {
        const int ls = 2 * s;
        const int j = t;
        float2 v0 = sb[SW(j)];
        float2 v1 = sb[SW(j + 512)];
        float2 v2 = sb[SW(j + 1024)];
        float2 v3 = sb[SW(j + 1536)];
        int jm = j & (Ns - 1);
        float c1, s1;
        if (s <= 2) {
            // few distinct addresses -> broadcast-cheap table read
            float2 e1 = expk[jm << (12 - 2 * s)];   // exp(i*pi*jm/(2*Ns))
            c1 = e1.x; s1 = e1.y;
        } else {
            // large stride gather would touch 64 lines; sincos is cheaper
            __sincosf((0.5f * PI_F) * (float)jm / (float)Ns, &s1, &c1);
        }
        float c2 = c1 * c1 - s1 * s1, s2 = 2.0f * c1 * s1;
        float c3 = c1 * c2 - s1 * s2, s3 = c1 * s2 + s1 * c2;
        v1 = cmulf(v1, c1, s1);
        v2 = cmulf(v2, c2, s2);
        v3 = cmulf(v3, c3, s3);
        float a0r = v0.x + v2.x, a0i = v0.y + v2.y;
        float a1r = v0.x - v2.x, a1i = v0.y - v2.y;
        float a2r = v1.x + v3.x, a2i = v1.y + v3.y;
        float a3r = v1.x - v3.x, a3i = v1.y - v3.y;
        int idxD = ((j >> ls) << (ls + 2)) | jm;
        db[SW(idxD)]          = make_float2(a0r + a2r, a0i + a2i);
        db[SW(idxD + Ns)]     = make_float2(a1r - a3i, a1i + a3r);
        db[SW(idxD + 2 * Ns)] = make_float2(a0r - a2r, a0i - a2i);
        db[SW(idxD + 3 * Ns)] = make_float2(a1r + a3i, a1i - a3r);
        __syncthreads();
        float2* tmp = sb; sb = db; db = tmp;
        Ns <<= 2;
    }
    // after 4 swaps: sb == bufA holds the radix-2 stage input

    // ---- fused radix-2 (Ns=1024) + de-interleave + float4 store ----
    // thread t handles the pair (j = t, jB = 1023-t) -> outputs p=j and p=jB
    // y_{4p}=Re z_p; y_{4p+1}=Im z_{2047-p}; y_{4p+2}=Im z_p; y_{4p+3}=Re z_{2047-p}
    {
        int j  = t;
        int jB = 1023 - t;
        float2 a0 = sb[SW(j)];
        float2 a1 = sb[SW(j + 1024)];
        float2 b0 = sb[SW(jB)];
        float2 b1 = sb[SW(jB + 1024)];
        float sA, cA, sB, cB;
        __sincosf(PI_F * (float)j  * (1.0f / 1024.0f), &sA, &cA);
        __sincosf(PI_F * (float)jB * (1.0f / 1024.0f), &sB, &cB);
        float2 wa1 = cmulf(a1, cA, sA);
        float2 wb1 = cmulf(b1, cB, sB);
        float2 zA0 = make_float2(a0.x + wa1.x, a0.y + wa1.y);   // z[j]
        float2 zA1 = make_float2(a0.x - wa1.x, a0.y - wa1.y);   // z[j+1024]
        float2 zB0 = make_float2(b0.x + wb1.x, b0.y + wb1.y);   // z[jB]
        float2 zB1 = make_float2(b0.x - wb1.x, b0.y - wb1.y);   // z[2047-j]
        float4 oA, oB;
        if (IDXST) {
            oA = make_float4(zA0.x, -zB1.y, zA0.y, -zB1.x);
            oB = make_float4(zB0.x, -zA1.y, zB0.y, -zA1.x);
        } else {
            oA = make_float4(zA0.x,  zB1.y, zA0.y,  zB1.x);
            oB = make_float4(zB0.x,  zA1.y, zB0.y,  zA1.x);
        }
        float4* d4 = (float4*)dst;
        d4[j]  = oA;
        d4[jB] = oB;
    }
}

// In-place per-batch square transpose (n x n), 64x64 tile pairs.
// float4 global loads AND stores; scalar LDS ops into padded tiles
// (bank = (4*c4 + j + r) mod 32 is at most 2-way = free).
__global__ __launch_bounds__(256)
void transpose_inplace(float* d, int n)
{
    __shared__ float ta[64][65];
    __shared__ float tb[64][65];
    int ti = blockIdx.x, tj = blockIdx.y, b = blockIdx.z;
    if (tj < ti) return;
    float* base = d + (size_t)b * n * n;
    const int t  = threadIdx.x;               // 0..255
    const int c4 = t & 15;                    // float4 column
    const int r0 = t >> 4;                    // 0..15
    size_t offA = (size_t)(ti * 64) * n + tj * 64;
    size_t offB = (size_t)(tj * 64) * n + ti * 64;

    #pragma unroll
    for (int q = 0; q < 4; q++) {
        int r = r0 + 16 * q;
        float4 va = ((const float4*)(base + offA + (size_t)r * n))[c4];
        ta[r][4 * c4 + 0] = va.x; ta[r][4 * c4 + 1] = va.y;
        ta[r][4 * c4 + 2] = va.z; ta[r][4 * c4 + 3] = va.w;
    }
    if (ti != tj) {
        #pragma unroll
        for (int q = 0; q < 4; q++) {
            int r = r0 + 16 * q;
            float4 vb = ((const float4*)(base + offB + (size_t)r * n))[c4];
            tb[r][4 * c4 + 0] = vb.x; tb[r][4 * c4 + 1] = vb.y;
            tb[r][4 * c4 + 2] = vb.z; tb[r][4 * c4 + 3] = vb.w;
        }
    }
    __syncthreads();

    if (ti != tj) {
        #pragma unroll
        for (int q = 0; q < 4; q++) {
            int r = r0 + 16 * q;
            float4 o;
            o.x = tb[4 * c4 + 0][r]; o.y = tb[4 * c4 + 1][r];
            o.z = tb[4 * c4 + 2][r]; o.w = tb[4 * c4 + 3][r];
            ((float4*)(base + offA + (size_t)r * n))[c4] = o;
            float4 p;
            p.x = ta[4 * c4 + 0][r]; p.y = ta[4 * c4 + 1][r];
            p.z = ta[4 * c4 + 2][r]; p.w = ta[4 * c4 + 3][r];
            ((float4*)(base + offB + (size_t)r * n))[c4] = p;
        }
    } else {
        #pragma unroll
        for (int q = 0; q < 4; q++) {
            int r = r0 + 16 * q;
            float4 p;
            p.x = ta[4 * c4 + 0][r]; p.y = ta[4 * c4 + 1][r];
            p.z = ta[4 * c4 + 2][r]; p.w = ta[4 * c4 + 3][r];
            ((float4*)(base + offA + (size_t)r * n))[c4] = p;
        }
    }
}

extern "C" void kernel_launch(void* const* d_in, const int* in_sizes, int n_in,
                              void* d_out, int out_size, void* d_ws, size_t ws_size,
                              hipStream_t stream)
{
    const float*  x     = (const float*)d_in[0];
    const float2* expkM = (const float2*)d_in[1];   // (4096, 2) fp32
    const float2* expkN = (const float2*)d_in[2];   // (4096, 2) fp32
    float* out = (float*)d_out;

    const int B = in_sizes[0] / (4096 * 4096);      // = 2
    const int rows = B * 4096;

    // IDXST along N (contiguous rows of x) -> out.  (Transforms on M and N commute.)
    row_fft_kernel<true><<<rows, 512, 0, stream>>>(x, out, expkN);
    // out: (B, M, N) -> (B, N, M)
    transpose_inplace<<<dim3(64, 64, B), dim3(256), 0, stream>>>(out, 4096);
    // IDCT along M (now-contiguous rows), in place.
    row_fft_kernel<false><<<rows, 512, 0, stream>>>(out, out, expkM);
    // back to (B, M, N)
    transpose_inplace<<<dim3(64, 64, B), dim3(256), 0, stream>>>(out, 4096);
}